// Round 3
// baseline (582.582 us; speedup 1.0000x reference)
//
#include <hip/hip_runtime.h>

#define NSEG   800
#define BATCH  256
#define NFREQ  51
#define NELEM  (BATCH*NFREQ)      // 13056
#define NSAMP  80000
#define NSLAB  800                // K1 blocks: 400 fake + 400 real, 2 segments each
#define NJ     16                 // reduce split
#define GPJ2   25                 // slabs per reduce group (400/16)
#define XSTR   136                // shorts per staged row (16B-mult, covers k 0..127 + pad)

typedef __attribute__((ext_vector_type(8))) short          short8;    // 8 bf16 = 4 VGPR
typedef __attribute__((ext_vector_type(4))) float          float4v;   // MFMA acc
typedef __attribute__((ext_vector_type(4))) unsigned short ushort4v;

// ---------------- compile-time window + trig (double Taylor, exact to fp32) ----------------
constexpr double TCPI  = 3.14159265358979323846264338327950288;
constexpr double TC2PI = 6.28318530717958647692528676655900577;

constexpr double taylor_cos(double y) {   // |y| <= pi
    double y2 = y * y, term = 1.0, sum = 1.0;
    for (int j = 1; j <= 26; ++j) { term *= -y2 / (double)((2*j-1)*(2*j)); sum += term; }
    return sum;
}
constexpr double cos_k(int k) {           // cos(2*pi*(k%100)/100)
    return -taylor_cos(TC2PI * (double)(k % 100) / 100.0 - TCPI);
}
struct WinT { float w[100]; };
constexpr WinT make_win() {
    WinT t{};
    for (int k = 0; k < 100; ++k) t.w[k] = (float)(1.0 - cos_k(k));   // hann(periodic)*2
    return t;
}
__device__ const WinT d_wt = make_win();

struct TrigT { float c[100]; float s[100]; };
constexpr TrigT make_trig() {
    TrigT t{};
    for (int m = 0; m < 100; ++m) {
        t.c[m] = (float)cos_k(m);                 // cos(2*pi*m/100)
        t.s[m] = (float)cos_k((m + 75) % 100);    // sin(2*pi*m/100) = cos(2*pi*(m+75)/100)
    }
    return t;
}
__device__ const TrigT d_tt = make_trig();

// ---------------- bf16 helpers (RN-even) ----------------
__device__ __forceinline__ unsigned short f2bf(float x) {
    unsigned int u = __float_as_uint(x);
    return (unsigned short)((u + 0x7FFFu + ((u >> 16) & 1u)) >> 16);
}
__device__ __forceinline__ float bf2f(unsigned short h) {
    return __uint_as_float(((unsigned int)h) << 16);
}

// order-preserving float<->uint key (monotone; min/max commutative => deterministic)
__device__ __forceinline__ unsigned int f2key(float x) {
    unsigned int b = __float_as_uint(x);
    return (b & 0x80000000u) ? ~b : (b | 0x80000000u);
}
__device__ __forceinline__ float key2f(unsigned int k) {
    return __uint_as_float((k & 0x80000000u) ? (k ^ 0x80000000u) : ~k);
}

// ---------------- K0: twiddle tables in MFMA B-frag order ----------------
// tw[pt][lane][j], pt=(kt*4+nt)*4+typ, typ: 0=Chi 1=Clo 2=Shi 3=Slo
// B[k=quad*8+j][f=lane&15]; zero for f>=51 or k>=100
__global__ void gen_tw_kernel(unsigned short* __restrict__ tw)
{
    int tid  = blockIdx.x * 256 + threadIdx.x;   // < 4096
    int lane = tid & 63, pt = tid >> 6;          // pt < 64
    int typ = pt & 3, nt = (pt >> 2) & 3, kt = pt >> 4;
    int f    = nt * 16 + (lane & 15);
    #pragma unroll
    for (int j = 0; j < 8; ++j) {
        int n = kt * 32 + (lane >> 4) * 8 + j;
        unsigned short outv = 0;
        if (f < 51 && n < 100) {
            int m = (n * f) % 100;
            float c = (typ < 2) ? d_tt.c[m] : d_tt.s[m];
            unsigned short h = f2bf(c);
            outv = (typ & 1) ? f2bf(c - bf2f(h)) : h;
        }
        tw[(pt << 9) + (lane << 3) + j] = outv;
    }
}

// ---------------- K1: 2 segments/block, coalesced LDS staging, MFMA DFT, ----------------
// atomic-key min/max (no Lb buffer), normalized values accumulated into csum registers.
// LDS ~71.7 KB -> 2 blocks/CU (4 waves/EU).
__global__ void __launch_bounds__(512) __attribute__((amdgpu_waves_per_eu(4)))
psd_seg_kernel(const float* __restrict__ fake, const float* __restrict__ real,
               float* __restrict__ pb2, float* __restrict__ saArr,
               const unsigned short* __restrict__ tw)
{
    __shared__ __align__(16) unsigned short xsh[BATCH * XSTR];   // 69632 B
    __shared__ unsigned int mnU[256], mxU[256];
    __shared__ float red8[8];

    const int bx = blockIdx.x;              // < 800
    const int isReal = bx >= 400;
    const int base   = bx - (isReal ? 400 : 0);
    const int t  = threadIdx.x;
    const int lane = t & 63, wv = t >> 6;
    const int col = lane & 15, quad = lane >> 4;
    const float4* __restrict__ src4 = (const float4*)(isReal ? real : fake);
    const float4* __restrict__ w4   = (const float4*)d_wt.w;

    // init atomic arrays (visible at first in-loop barrier)
    if (t < 256) mnU[t] = 0xFFFFFFFFu;
    else         mxU[t - 256] = 0u;

    float csum[2][2][2][4] = {};            // [fh][mt][ntl][reg] column-sum accumulators
    const bool v3 = (col < 3);              // f<51 for nt==3

    #pragma unroll 1
    for (int seg = 0; seg < 2; ++seg) {
        const int s = 2 * base + seg;

        // ---- stage: 6400 coalesced float4 loads -> clamp/window -> bf16 short4 stores ----
        #pragma unroll
        for (int it = 0; it < 13; ++it) {
            int idx = t + it * 512;
            if (idx < 6400) {
                int row = idx / 25, q = idx - row * 25;          // q-th float4 of row
                float4 v  = src4[(size_t)row * (NSAMP / 4) + s * 25 + q];
                float4 ww = w4[q];
                ushort4v o;
                o.x = f2bf(fmaxf(v.x, 1e-6f) * ww.x);
                o.y = f2bf(fmaxf(v.y, 1e-6f) * ww.y);
                o.z = f2bf(fmaxf(v.z, 1e-6f) * ww.z);
                o.w = f2bf(fmaxf(v.w, 1e-6f) * ww.w);
                *(ushort4v*)(xsh + row * XSTR + 4 * q) = o;      // 8B-aligned
            }
        }
        // ---- zero-pad k-slots 100..127 (7 short4 per row) ----
        #pragma unroll
        for (int it = 0; it < 4; ++it) {
            int idx = t + it * 512;
            if (idx < 1792) {
                int row = idx / 7, q = idx - row * 7;
                ushort4v z = {0, 0, 0, 0};
                *(ushort4v*)(xsh + row * XSTR + 100 + 4 * q) = z;
            }
        }
        __syncthreads();

        // ---- two frequency passes over the same staged X; log-PSD kept in registers ----
        float Lv[2][2][2][4];                          // [fh][mt][ntl][reg] — static indices
        #pragma unroll 1
        for (int fh = 0; fh < 2; ++fh) {
            float4v accRe[2][2] = {};
            float4v accIm[2][2] = {};
            #pragma unroll
            for (int kt = 0; kt < 4; ++kt) {
                #pragma unroll
                for (int mt = 0; mt < 2; ++mt) {
                    const int row = 32 * wv + 16 * mt + col;     // A: m = lane&15
                    short8 xa = *(const short8*)(xsh + row * XSTR + kt * 32 + quad * 8);
                    #pragma unroll
                    for (int ntl = 0; ntl < 2; ++ntl) {
                        const int nt = fh * 2 + ntl;
                        const unsigned short* bp = tw + (size_t)((kt * 4 + nt) * 4) * 512 + (lane << 3);
                        short8 bCh = *(const short8*)(bp);
                        short8 bCl = *(const short8*)(bp + 512);
                        accRe[mt][ntl] = __builtin_amdgcn_mfma_f32_16x16x32_bf16(xa, bCh, accRe[mt][ntl], 0, 0, 0);
                        accRe[mt][ntl] = __builtin_amdgcn_mfma_f32_16x16x32_bf16(xa, bCl, accRe[mt][ntl], 0, 0, 0);
                        short8 bSh = *(const short8*)(bp + 1024);
                        short8 bSl = *(const short8*)(bp + 1536);
                        accIm[mt][ntl] = __builtin_amdgcn_mfma_f32_16x16x32_bf16(xa, bSh, accIm[mt][ntl], 0, 0, 0);
                        accIm[mt][ntl] = __builtin_amdgcn_mfma_f32_16x16x32_bf16(xa, bSl, accIm[mt][ntl], 0, 0, 0);
                    }
                }
            }
            // ---- PSD -> signed clamp log -> registers ----
            #pragma unroll
            for (int mt = 0; mt < 2; ++mt)
                #pragma unroll
                for (int ntl = 0; ntl < 2; ++ntl)
                    #pragma unroll
                    for (int reg = 0; reg < 4; ++reg) {
                        float re = accRe[mt][ntl][reg], im = accIm[mt][ntl][reg];
                        float p  = fmaf(re, re, im * im);
                        p        = fmaxf(p, 1e-38f);
                        float lv = __logf(p);
                        float al = fmaxf(fabsf(lv), 1e-6f);
                        Lv[fh][mt][ntl][reg] = (lv > 0.0f) ? al : ((lv < 0.0f) ? -al : 0.0f);
                    }
        }

        // ---- group min/max via LDS atomics on monotone keys (group c = flat & 255) ----
        #pragma unroll
        for (int fh = 0; fh < 2; ++fh)
            #pragma unroll
            for (int mt = 0; mt < 2; ++mt)
                #pragma unroll
                for (int ntl = 0; ntl < 2; ++ntl) {
                    const int nt = fh * 2 + ntl;
                    if (nt < 3 || v3) {
                        #pragma unroll
                        for (int reg = 0; reg < 4; ++reg) {
                            int row  = 32 * wv + 16 * mt + quad * 4 + reg;
                            int flat = row * 51 + nt * 16 + col;
                            int c    = flat & 255;
                            unsigned int key = f2key(Lv[fh][mt][ntl][reg]);
                            atomicMin(&mnU[c], key);
                            atomicMax(&mxU[c], key);
                        }
                    }
                }
        __syncthreads();
        if (t < 256) {
            float fmn = key2f(mnU[t]);
            float fmx = key2f(mxU[t]);
            mnU[t] = __float_as_uint(fmn);
            mxU[t] = __float_as_uint(1.0f / (fmx - fmn));
        }
        __syncthreads();

        // ---- normalize from registers -> csum accumulate + ssq ----
        float ssq = 0.0f;
        #pragma unroll
        for (int fh = 0; fh < 2; ++fh)
            #pragma unroll
            for (int mt = 0; mt < 2; ++mt)
                #pragma unroll
                for (int ntl = 0; ntl < 2; ++ntl) {
                    const int nt = fh * 2 + ntl;
                    if (nt < 3 || v3) {
                        #pragma unroll
                        for (int reg = 0; reg < 4; ++reg) {
                            int row  = 32 * wv + 16 * mt + quad * 4 + reg;
                            int flat = row * 51 + nt * 16 + col;
                            int c    = flat & 255;
                            float mn  = __uint_as_float(mnU[c]);
                            float inv = __uint_as_float(mxU[c]);
                            float F = (Lv[fh][mt][ntl][reg] - mn) * inv;
                            ssq = fmaf(F, F, ssq);
                            csum[fh][mt][ntl][reg] += F;
                        }
                    }
                }

        #pragma unroll
        for (int off = 32; off; off >>= 1) ssq += __shfl_down(ssq, off, 64);
        if (lane == 0) red8[wv] = ssq;
        __syncthreads();     // red8 ready; all mnU/mxU reads done
        if (t == 0) {
            float acc = 0.0f;
            #pragma unroll
            for (int i = 0; i < 8; ++i) acc += red8[i];
            saArr[(size_t)isReal * NSEG + s] = acc;
        }
        if (seg == 0) {      // reset for next segment (visible at next in-loop barrier)
            if (t < 256) mnU[t] = 0xFFFFFFFFu;
            else         mxU[t - 256] = 0u;
        }
    }

    // ---- write per-slab column sums (41.8 MB total vs 83.6 for full part) ----
    float* __restrict__ dst = pb2 + (size_t)bx * NELEM;
    #pragma unroll
    for (int fh = 0; fh < 2; ++fh)
        #pragma unroll
        for (int mt = 0; mt < 2; ++mt)
            #pragma unroll
            for (int ntl = 0; ntl < 2; ++ntl) {
                const int nt = fh * 2 + ntl;
                if (nt < 3 || v3) {
                    #pragma unroll
                    for (int reg = 0; reg < 4; ++reg) {
                        int row  = 32 * wv + 16 * mt + quad * 4 + reg;
                        int flat = row * 51 + nt * 16 + col;
                        dst[flat] = csum[fh][mt][ntl][reg];
                    }
                }
            }
}

// ---------------- K2a: partial column sums over 25-slab groups ----------------
__global__ void reduce_part_kernel(const float* __restrict__ pb2, float* __restrict__ pb)
{
    const int e = blockIdx.x * 256 + threadIdx.x;   // < 13056
    const int j = blockIdx.y;                        // < NJ
    const float* __restrict__ pF = pb2 + (size_t)(j * GPJ2) * NELEM + e;
    const float* __restrict__ pR = pb2 + (size_t)(400 + j * GPJ2) * NELEM + e;
    float sF = 0.0f, sR = 0.0f;
    #pragma unroll 5
    for (int i = 0; i < GPJ2; ++i) {
        sF += pF[(size_t)i * NELEM];
        sR += pR[(size_t)i * NELEM];
    }
    pb[(size_t)(2 * j + 0) * NELEM + e] = sF;
    pb[(size_t)(2 * j + 1) * NELEM + e] = sR;
}

// ---------------- K2b: finish sums, per-e dot/ff, block reduce ----------------
__global__ void dot_kernel(const float* __restrict__ pb, double* __restrict__ k2out)
{
    __shared__ double red[2][4];
    const int t = threadIdx.x;
    const int e = blockIdx.x * 256 + t;
    float sF = 0.0f, sR = 0.0f;
    #pragma unroll
    for (int j = 0; j < NJ; ++j) {
        sF += pb[(size_t)(2 * j + 0) * NELEM + e];
        sR += pb[(size_t)(2 * j + 1) * NELEM + e];
    }
    double d  = (double)sF * (double)sR;
    double f2 = (double)sF * (double)sF;
    #pragma unroll
    for (int off = 32; off; off >>= 1) {
        d  += __shfl_down(d,  off, 64);
        f2 += __shfl_down(f2, off, 64);
    }
    if ((t & 63) == 0) { red[0][t >> 6] = d; red[1][t >> 6] = f2; }
    __syncthreads();
    if (t == 0) {
        k2out[2 * blockIdx.x + 0] = red[0][0] + red[0][1] + red[0][2] + red[0][3];
        k2out[2 * blockIdx.x + 1] = red[1][0] + red[1][1] + red[1][2] + red[1][3];
    }
}

// ---------------- K3: final combine in double ----------------
__global__ void final_kernel(const double* __restrict__ k2out, const float* __restrict__ saArr,
                             float* __restrict__ out)
{
    __shared__ double red[4][4];
    const int t = threadIdx.x;
    double d = 0.0, f2 = 0.0, sf = 0.0, sr = 0.0;
    if (t < NFREQ) { d = k2out[2 * t]; f2 = k2out[2 * t + 1]; }
    for (int i = t; i < NSEG; i += 256) {
        sf += (double)saArr[i];
        sr += (double)saArr[NSEG + i];
    }
    #pragma unroll
    for (int off = 32; off; off >>= 1) {
        d  += __shfl_down(d,  off, 64);
        f2 += __shfl_down(f2, off, 64);
        sf += __shfl_down(sf, off, 64);
        sr += __shfl_down(sr, off, 64);
    }
    const int w = t >> 6;
    if ((t & 63) == 0) { red[0][w] = d; red[1][w] = f2; red[2][w] = sf; red[3][w] = sr; }
    __syncthreads();
    if (t == 0) {
        double D  = red[0][0] + red[0][1] + red[0][2] + red[0][3];
        double FF = red[1][0] + red[1][1] + red[1][2] + red[1][3];
        double SF = red[2][0] + red[2][1] + red[2][2] + red[2][3];
        double SR = red[3][0] + red[3][1] + red[3][2] + red[3][3];

        const double n    = (double)NELEM;
        const double nseg = (double)NSEG;
        const double m    = nseg * (nseg - 1.0) * 0.5;

        out[0] = (float)((SF / nseg + SR / nseg - 2.0 * D / (nseg * nseg)) / n);
        out[1] = (float)((nseg * SF - FF) / (n * m));
    }
}

extern "C" void kernel_launch(void* const* d_in, const int* in_sizes, int n_in,
                              void* d_out, int out_size, void* d_ws, size_t ws_size,
                              hipStream_t stream) {
    const float* fake = (const float*)d_in[0];
    const float* real = (const float*)d_in[1];
    float* ws  = (float*)d_ws;
    float* out = (float*)d_out;

    // ws (floats): pb2[800*13056] | saArr[1600] | pb[2*NJ*13056] | k2out (doubles) | tw (64KB)
    const size_t SA_FL = (size_t)NSLAB * NELEM;           // 10,444,800
    const size_t PB_FL = SA_FL + 2 * NSEG;
    const size_t K2_BY = (PB_FL + (size_t)2 * NJ * NELEM) * 4;         // 8B-aligned
    const size_t TW_BY = (K2_BY + 2 * NFREQ * sizeof(double) + 63) & ~(size_t)63;

    float*          sa = ws + SA_FL;
    float*          pb = ws + PB_FL;
    double*         k2 = (double*)((char*)d_ws + K2_BY);
    unsigned short* tw = (unsigned short*)((char*)d_ws + TW_BY);

    gen_tw_kernel<<<16, 256, 0, stream>>>(tw);
    psd_seg_kernel<<<NSLAB, 512, 0, stream>>>(fake, real, ws, sa, tw);
    reduce_part_kernel<<<dim3(NFREQ, NJ), 256, 0, stream>>>(ws, pb);
    dot_kernel<<<NFREQ, 256, 0, stream>>>(pb, k2);
    final_kernel<<<1, 256, 0, stream>>>(k2, sa, out);
}

// Round 4
// 410.286 us; speedup vs baseline: 1.4199x; 1.4199x over previous
//
#include <hip/hip_runtime.h>

#define NSEG   800
#define BATCH  256
#define NFREQ  51
#define NELEM  (BATCH*NFREQ)      // 13056
#define NSAMP  80000
#define NSLAB  800                // K1 blocks: 400 fake + 400 real, 2 segments each
#define NJ     16                 // reduce split
#define GPJ2   25                 // slabs per reduce group (400/16)
#define XSTR   136                // shorts per staged row (16B-mult, covers k 0..127 + pad)

typedef __attribute__((ext_vector_type(8))) short          short8;    // 8 bf16 = 4 VGPR
typedef __attribute__((ext_vector_type(4))) float          float4v;   // MFMA acc
typedef __attribute__((ext_vector_type(4))) unsigned short ushort4v;

// ---------------- compile-time window + trig (double Taylor, exact to fp32) ----------------
constexpr double TCPI  = 3.14159265358979323846264338327950288;
constexpr double TC2PI = 6.28318530717958647692528676655900577;

constexpr double taylor_cos(double y) {   // |y| <= pi
    double y2 = y * y, term = 1.0, sum = 1.0;
    for (int j = 1; j <= 26; ++j) { term *= -y2 / (double)((2*j-1)*(2*j)); sum += term; }
    return sum;
}
constexpr double cos_k(int k) {           // cos(2*pi*(k%100)/100)
    return -taylor_cos(TC2PI * (double)(k % 100) / 100.0 - TCPI);
}
struct WinT { float w[100]; };
constexpr WinT make_win() {
    WinT t{};
    for (int k = 0; k < 100; ++k) t.w[k] = (float)(1.0 - cos_k(k));   // hann(periodic)*2
    return t;
}
__device__ const WinT d_wt = make_win();

struct TrigT { float c[100]; float s[100]; };
constexpr TrigT make_trig() {
    TrigT t{};
    for (int m = 0; m < 100; ++m) {
        t.c[m] = (float)cos_k(m);                 // cos(2*pi*m/100)
        t.s[m] = (float)cos_k((m + 75) % 100);    // sin = cos shifted by 3/4 period
    }
    return t;
}
__device__ const TrigT d_tt = make_trig();

// ---------------- bf16 helpers (RN-even) ----------------
__device__ __forceinline__ unsigned short f2bf(float x) {
    unsigned int u = __float_as_uint(x);
    return (unsigned short)((u + 0x7FFFu + ((u >> 16) & 1u)) >> 16);
}
__device__ __forceinline__ float bf2f(unsigned short h) {
    return __uint_as_float(((unsigned int)h) << 16);
}

// order-preserving float<->uint key (monotone; min/max commutative => deterministic)
__device__ __forceinline__ unsigned int f2key(float x) {
    unsigned int b = __float_as_uint(x);
    return (b & 0x80000000u) ? ~b : (b | 0x80000000u);
}
__device__ __forceinline__ float key2f(unsigned int k) {
    return __uint_as_float((k & 0x80000000u) ? (k ^ 0x80000000u) : ~k);
}

// ---------------- K0: twiddle tables in MFMA B-frag order ----------------
__global__ void gen_tw_kernel(unsigned short* __restrict__ tw)
{
    int tid  = blockIdx.x * 256 + threadIdx.x;   // < 4096
    int lane = tid & 63, pt = tid >> 6;          // pt < 64
    int typ = pt & 3, nt = (pt >> 2) & 3, kt = pt >> 4;
    int f    = nt * 16 + (lane & 15);
    #pragma unroll
    for (int j = 0; j < 8; ++j) {
        int n = kt * 32 + (lane >> 4) * 8 + j;
        unsigned short outv = 0;
        if (f < 51 && n < 100) {
            int m = (n * f) % 100;
            float c = (typ < 2) ? d_tt.c[m] : d_tt.s[m];
            unsigned short h = f2bf(c);
            outv = (typ & 1) ? f2bf(c - bf2f(h)) : h;
        }
        tw[(pt << 9) + (lane << 3) + j] = outv;
    }
}

// ======== K1 macros — ALL private-array indices compile-time (rule #20) ========

// one frequency-half DFT: 32 MFMAs + PSD + signed-clamp-log into LVOUT[2][2][4]
#define DFT_PASS(FH, LVOUT)                                                        \
  {                                                                                \
    float4v accRe_[2][2] = {}; float4v accIm_[2][2] = {};                          \
    _Pragma("unroll")                                                              \
    for (int kt = 0; kt < 4; ++kt) {                                               \
      short8 xa0 = *(const short8*)(xsh + (32*wv +      col) * XSTR + kt*32 + quad*8); \
      short8 xa1 = *(const short8*)(xsh + (32*wv + 16 + col) * XSTR + kt*32 + quad*8); \
      _Pragma("unroll")                                                            \
      for (int ntl = 0; ntl < 2; ++ntl) {                                          \
        const unsigned short* bp_ = tw + (size_t)((kt*4 + (FH)*2 + ntl)*4)*512 + (lane<<3); \
        short8 bCh = *(const short8*)(bp_);                                        \
        short8 bCl = *(const short8*)(bp_ + 512);                                  \
        short8 bSh = *(const short8*)(bp_ + 1024);                                 \
        short8 bSl = *(const short8*)(bp_ + 1536);                                 \
        accRe_[0][ntl] = __builtin_amdgcn_mfma_f32_16x16x32_bf16(xa0, bCh, accRe_[0][ntl],0,0,0); \
        accRe_[0][ntl] = __builtin_amdgcn_mfma_f32_16x16x32_bf16(xa0, bCl, accRe_[0][ntl],0,0,0); \
        accIm_[0][ntl] = __builtin_amdgcn_mfma_f32_16x16x32_bf16(xa0, bSh, accIm_[0][ntl],0,0,0); \
        accIm_[0][ntl] = __builtin_amdgcn_mfma_f32_16x16x32_bf16(xa0, bSl, accIm_[0][ntl],0,0,0); \
        accRe_[1][ntl] = __builtin_amdgcn_mfma_f32_16x16x32_bf16(xa1, bCh, accRe_[1][ntl],0,0,0); \
        accRe_[1][ntl] = __builtin_amdgcn_mfma_f32_16x16x32_bf16(xa1, bCl, accRe_[1][ntl],0,0,0); \
        accIm_[1][ntl] = __builtin_amdgcn_mfma_f32_16x16x32_bf16(xa1, bSh, accIm_[1][ntl],0,0,0); \
        accIm_[1][ntl] = __builtin_amdgcn_mfma_f32_16x16x32_bf16(xa1, bSl, accIm_[1][ntl],0,0,0); \
      }                                                                            \
    }                                                                              \
    _Pragma("unroll")                                                              \
    for (int mt = 0; mt < 2; ++mt)                                                 \
      _Pragma("unroll")                                                            \
      for (int ntl = 0; ntl < 2; ++ntl)                                            \
        _Pragma("unroll")                                                          \
        for (int reg = 0; reg < 4; ++reg) {                                        \
          float re_ = accRe_[mt][ntl][reg], im_ = accIm_[mt][ntl][reg];            \
          float p_  = fmaf(re_, re_, im_ * im_);                                   \
          p_        = fmaxf(p_, 1e-38f);                                           \
          float lv_ = __logf(p_);                                                  \
          float al_ = fmaxf(fabsf(lv_), 1e-6f);                                    \
          LVOUT[mt][ntl][reg] = (lv_ > 0.0f) ? al_ : ((lv_ < 0.0f) ? -al_ : 0.0f); \
        }                                                                          \
  }

#define MINMAX_ATOM(LV, FH, SET)                                                   \
  _Pragma("unroll")                                                                \
  for (int mt = 0; mt < 2; ++mt)                                                   \
    _Pragma("unroll")                                                              \
    for (int ntl = 0; ntl < 2; ++ntl) {                                            \
      const int nt_ = (FH)*2 + ntl;                                                \
      if (nt_ < 3 || v3) {                                                         \
        _Pragma("unroll")                                                          \
        for (int reg = 0; reg < 4; ++reg) {                                        \
          int flat_ = (32*wv + 16*mt + quad*4 + reg) * 51 + nt_*16 + col;          \
          unsigned int key_ = f2key(LV[mt][ntl][reg]);                             \
          atomicMin(&mnU[SET][flat_ & 255], key_);                                 \
          atomicMax(&mxU[SET][flat_ & 255], key_);                                 \
        }                                                                          \
      }                                                                            \
    }

#define NORM_ACC(LV, FH, SET)                                                      \
  _Pragma("unroll")                                                                \
  for (int mt = 0; mt < 2; ++mt)                                                   \
    _Pragma("unroll")                                                              \
    for (int ntl = 0; ntl < 2; ++ntl) {                                            \
      const int nt_ = (FH)*2 + ntl;                                                \
      if (nt_ < 3 || v3) {                                                         \
        _Pragma("unroll")                                                          \
        for (int reg = 0; reg < 4; ++reg) {                                        \
          int flat_ = (32*wv + 16*mt + quad*4 + reg) * 51 + nt_*16 + col;          \
          int c_    = flat_ & 255;                                                 \
          float mn_  = __uint_as_float(mnU[SET][c_]);                              \
          float inv_ = __uint_as_float(mxU[SET][c_]);                              \
          float F_ = (LV[mt][ntl][reg] - mn_) * inv_;                              \
          ssq = fmaf(F_, F_, ssq);                                                 \
          csum[(FH)][mt][ntl][reg] += F_;                                          \
        }                                                                          \
      }                                                                            \
    }

// ---------------- K1: 2 segments/block, linear code, static indexing ----------------
// LDS 73.8 KB -> 2 blocks/CU (4 waves/EU). Prefetch of seg1 overlaps seg0 epilogue.
__global__ void __launch_bounds__(512) __attribute__((amdgpu_waves_per_eu(4)))
psd_seg_kernel(const float* __restrict__ fake, const float* __restrict__ real,
               float* __restrict__ pb2, float* __restrict__ saArr,
               const unsigned short* __restrict__ tw)
{
    __shared__ __align__(16) unsigned short xsh[BATCH * XSTR];   // 69632 B
    __shared__ unsigned int mnU[2][256], mxU[2][256];            // per-seg min/max sets
    __shared__ float red8[2][8];

    const int bx = blockIdx.x;              // < 800
    const int isReal = bx >= 400;
    const int base   = bx - (isReal ? 400 : 0);
    const int t  = threadIdx.x;
    const int lane = t & 63, wv = t >> 6;
    const int col = lane & 15, quad = lane >> 4;
    const bool v3 = (col < 3);              // f<51 for nt==3
    const float4* __restrict__ src4 = (const float4*)(isReal ? real : fake);
    const float4* __restrict__ w4   = (const float4*)d_wt.w;
    const int s0 = 2 * base, s1 = 2 * base + 1;

    // init both min/max sets
    if (t < 256) { mnU[0][t] = 0xFFFFFFFFu; mnU[1][t] = 0xFFFFFFFFu; }
    else         { mxU[0][t - 256] = 0u;    mxU[1][t - 256] = 0u;    }

    float csum[2][2][2][4] = {};            // [fh][mt][ntl][reg] column-sum accumulators
    float LvA[2][2][4], LvB[2][2][4];       // log-PSD halves, all static indices

    // ---- SEG0 stage: 6400 coalesced float4 loads -> clamp/window -> bf16 stores ----
    #pragma unroll
    for (int it = 0; it < 13; ++it) {
        int idx = t + it * 512;
        if (idx < 6400) {
            int row = idx / 25, q = idx - row * 25;
            float4 v  = src4[(size_t)row * (NSAMP / 4) + s0 * 25 + q];
            float4 ww = w4[q];
            ushort4v o;
            o.x = f2bf(fmaxf(v.x, 1e-6f) * ww.x);
            o.y = f2bf(fmaxf(v.y, 1e-6f) * ww.y);
            o.z = f2bf(fmaxf(v.z, 1e-6f) * ww.z);
            o.w = f2bf(fmaxf(v.w, 1e-6f) * ww.w);
            *(ushort4v*)(xsh + row * XSTR + 4 * q) = o;
        }
    }
    // ---- zero-pad k-slots 100..127 — once; never overwritten by staging ----
    #pragma unroll
    for (int it = 0; it < 4; ++it) {
        int idx = t + it * 512;
        if (idx < 1792) {
            int row = idx / 7, q = idx - row * 7;
            ushort4v z = {0, 0, 0, 0};
            *(ushort4v*)(xsh + row * XSTR + 100 + 4 * q) = z;
        }
    }
    __syncthreads();                                   // B1: xsh(seg0) + set inits ready

    // ---- SEG0 compute ----
    DFT_PASS(0, LvA)
    DFT_PASS(1, LvB)
    MINMAX_ATOM(LvA, 0, 0)
    MINMAX_ATOM(LvB, 1, 0)
    __syncthreads();                                   // B2: xsh free, seg0 atomics done

    // ---- prefetch seg1 (first 8 float4/thread) — hides HBM under finalize+normalize ----
    float4 pf[8];
    #pragma unroll
    for (int it = 0; it < 8; ++it) {
        int idx = t + it * 512;                        // < 4096 < 6400, always valid
        int row = idx / 25, q = idx - row * 25;
        pf[it] = src4[(size_t)row * (NSAMP / 4) + s1 * 25 + q];
    }
    if (t < 256) {
        float fmn = key2f(mnU[0][t]);
        float fmx = key2f(mxU[0][t]);
        mnU[0][t] = __float_as_uint(fmn);
        mxU[0][t] = __float_as_uint(1.0f / (fmx - fmn));
    }
    __syncthreads();                                   // B3: set0 finalized

    {
        float ssq = 0.0f;
        NORM_ACC(LvA, 0, 0)
        NORM_ACC(LvB, 1, 0)
        #pragma unroll
        for (int off = 32; off; off >>= 1) ssq += __shfl_down(ssq, off, 64);
        if (lane == 0) red8[0][wv] = ssq;
    }

    // ---- consume prefetch + tail loads -> xsh(seg1) ----
    #pragma unroll
    for (int it = 0; it < 8; ++it) {
        int idx = t + it * 512;
        int row = idx / 25, q = idx - row * 25;
        float4 v  = pf[it];
        float4 ww = w4[q];
        ushort4v o;
        o.x = f2bf(fmaxf(v.x, 1e-6f) * ww.x);
        o.y = f2bf(fmaxf(v.y, 1e-6f) * ww.y);
        o.z = f2bf(fmaxf(v.z, 1e-6f) * ww.z);
        o.w = f2bf(fmaxf(v.w, 1e-6f) * ww.w);
        *(ushort4v*)(xsh + row * XSTR + 4 * q) = o;
    }
    #pragma unroll
    for (int it = 8; it < 13; ++it) {
        int idx = t + it * 512;
        if (idx < 6400) {
            int row = idx / 25, q = idx - row * 25;
            float4 v  = src4[(size_t)row * (NSAMP / 4) + s1 * 25 + q];
            float4 ww = w4[q];
            ushort4v o;
            o.x = f2bf(fmaxf(v.x, 1e-6f) * ww.x);
            o.y = f2bf(fmaxf(v.y, 1e-6f) * ww.y);
            o.z = f2bf(fmaxf(v.z, 1e-6f) * ww.z);
            o.w = f2bf(fmaxf(v.w, 1e-6f) * ww.w);
            *(ushort4v*)(xsh + row * XSTR + 4 * q) = o;
        }
    }
    __syncthreads();                                   // B4: xsh(seg1) + red8[0] ready
    if (t == 0) {
        float acc = 0.0f;
        #pragma unroll
        for (int i = 0; i < 8; ++i) acc += red8[0][i];
        saArr[(size_t)isReal * NSEG + s0] = acc;
    }

    // ---- SEG1 compute ----
    DFT_PASS(0, LvA)
    DFT_PASS(1, LvB)
    MINMAX_ATOM(LvA, 0, 1)
    MINMAX_ATOM(LvB, 1, 1)
    __syncthreads();                                   // B5: seg1 atomics done
    if (t < 256) {
        float fmn = key2f(mnU[1][t]);
        float fmx = key2f(mxU[1][t]);
        mnU[1][t] = __float_as_uint(fmn);
        mxU[1][t] = __float_as_uint(1.0f / (fmx - fmn));
    }
    __syncthreads();                                   // B6: set1 finalized

    {
        float ssq = 0.0f;
        NORM_ACC(LvA, 0, 1)
        NORM_ACC(LvB, 1, 1)
        #pragma unroll
        for (int off = 32; off; off >>= 1) ssq += __shfl_down(ssq, off, 64);
        if (lane == 0) red8[1][wv] = ssq;
    }
    __syncthreads();                                   // B7: red8[1] ready
    if (t == 0) {
        float acc = 0.0f;
        #pragma unroll
        for (int i = 0; i < 8; ++i) acc += red8[1][i];
        saArr[(size_t)isReal * NSEG + s1] = acc;
    }

    // ---- write per-slab column sums (seg0+seg1), 13056 floats ----
    float* __restrict__ dst = pb2 + (size_t)bx * NELEM;
    #pragma unroll
    for (int fh = 0; fh < 2; ++fh)
        #pragma unroll
        for (int mt = 0; mt < 2; ++mt)
            #pragma unroll
            for (int ntl = 0; ntl < 2; ++ntl) {
                const int nt = fh * 2 + ntl;
                if (nt < 3 || v3) {
                    #pragma unroll
                    for (int reg = 0; reg < 4; ++reg) {
                        int flat = (32 * wv + 16 * mt + quad * 4 + reg) * 51 + nt * 16 + col;
                        dst[flat] = csum[fh][mt][ntl][reg];
                    }
                }
            }
}

// ---------------- K2a: partial column sums over 25-slab groups ----------------
__global__ void reduce_part_kernel(const float* __restrict__ pb2, float* __restrict__ pb)
{
    const int e = blockIdx.x * 256 + threadIdx.x;   // < 13056
    const int j = blockIdx.y;                        // < NJ
    const float* __restrict__ pF = pb2 + (size_t)(j * GPJ2) * NELEM + e;
    const float* __restrict__ pR = pb2 + (size_t)(400 + j * GPJ2) * NELEM + e;
    float sF = 0.0f, sR = 0.0f;
    #pragma unroll 5
    for (int i = 0; i < GPJ2; ++i) {
        sF += pF[(size_t)i * NELEM];
        sR += pR[(size_t)i * NELEM];
    }
    pb[(size_t)(2 * j + 0) * NELEM + e] = sF;
    pb[(size_t)(2 * j + 1) * NELEM + e] = sR;
}

// ---------------- K2b: finish sums, per-e dot/ff, block reduce ----------------
__global__ void dot_kernel(const float* __restrict__ pb, double* __restrict__ k2out)
{
    __shared__ double red[2][4];
    const int t = threadIdx.x;
    const int e = blockIdx.x * 256 + t;
    float sF = 0.0f, sR = 0.0f;
    #pragma unroll
    for (int j = 0; j < NJ; ++j) {
        sF += pb[(size_t)(2 * j + 0) * NELEM + e];
        sR += pb[(size_t)(2 * j + 1) * NELEM + e];
    }
    double d  = (double)sF * (double)sR;
    double f2 = (double)sF * (double)sF;
    #pragma unroll
    for (int off = 32; off; off >>= 1) {
        d  += __shfl_down(d,  off, 64);
        f2 += __shfl_down(f2, off, 64);
    }
    if ((t & 63) == 0) { red[0][t >> 6] = d; red[1][t >> 6] = f2; }
    __syncthreads();
    if (t == 0) {
        k2out[2 * blockIdx.x + 0] = red[0][0] + red[0][1] + red[0][2] + red[0][3];
        k2out[2 * blockIdx.x + 1] = red[1][0] + red[1][1] + red[1][2] + red[1][3];
    }
}

// ---------------- K3: final combine in double ----------------
__global__ void final_kernel(const double* __restrict__ k2out, const float* __restrict__ saArr,
                             float* __restrict__ out)
{
    __shared__ double red[4][4];
    const int t = threadIdx.x;
    double d = 0.0, f2 = 0.0, sf = 0.0, sr = 0.0;
    if (t < NFREQ) { d = k2out[2 * t]; f2 = k2out[2 * t + 1]; }
    for (int i = t; i < NSEG; i += 256) {
        sf += (double)saArr[i];
        sr += (double)saArr[NSEG + i];
    }
    #pragma unroll
    for (int off = 32; off; off >>= 1) {
        d  += __shfl_down(d,  off, 64);
        f2 += __shfl_down(f2, off, 64);
        sf += __shfl_down(sf, off, 64);
        sr += __shfl_down(sr, off, 64);
    }
    const int w = t >> 6;
    if ((t & 63) == 0) { red[0][w] = d; red[1][w] = f2; red[2][w] = sf; red[3][w] = sr; }
    __syncthreads();
    if (t == 0) {
        double D  = red[0][0] + red[0][1] + red[0][2] + red[0][3];
        double FF = red[1][0] + red[1][1] + red[1][2] + red[1][3];
        double SF = red[2][0] + red[2][1] + red[2][2] + red[2][3];
        double SR = red[3][0] + red[3][1] + red[3][2] + red[3][3];

        const double n    = (double)NELEM;
        const double nseg = (double)NSEG;
        const double m    = nseg * (nseg - 1.0) * 0.5;

        out[0] = (float)((SF / nseg + SR / nseg - 2.0 * D / (nseg * nseg)) / n);
        out[1] = (float)((nseg * SF - FF) / (n * m));
    }
}

extern "C" void kernel_launch(void* const* d_in, const int* in_sizes, int n_in,
                              void* d_out, int out_size, void* d_ws, size_t ws_size,
                              hipStream_t stream) {
    const float* fake = (const float*)d_in[0];
    const float* real = (const float*)d_in[1];
    float* ws  = (float*)d_ws;
    float* out = (float*)d_out;

    // ws (floats): pb2[800*13056] | saArr[1600] | pb[2*NJ*13056] | k2out (doubles) | tw (64KB)
    const size_t SA_FL = (size_t)NSLAB * NELEM;           // 10,444,800
    const size_t PB_FL = SA_FL + 2 * NSEG;
    const size_t K2_BY = (PB_FL + (size_t)2 * NJ * NELEM) * 4;         // 8B-aligned
    const size_t TW_BY = (K2_BY + 2 * NFREQ * sizeof(double) + 63) & ~(size_t)63;

    float*          sa = ws + SA_FL;
    float*          pb = ws + PB_FL;
    double*         k2 = (double*)((char*)d_ws + K2_BY);
    unsigned short* tw = (unsigned short*)((char*)d_ws + TW_BY);

    gen_tw_kernel<<<16, 256, 0, stream>>>(tw);
    psd_seg_kernel<<<NSLAB, 512, 0, stream>>>(fake, real, ws, sa, tw);
    reduce_part_kernel<<<dim3(NFREQ, NJ), 256, 0, stream>>>(ws, pb);
    dot_kernel<<<NFREQ, 256, 0, stream>>>(pb, k2);
    final_kernel<<<1, 256, 0, stream>>>(k2, sa, out);
}

// Round 5
// 326.820 us; speedup vs baseline: 1.7826x; 1.2554x over previous
//
#include <hip/hip_runtime.h>

#define NSEG   800
#define BATCH  256
#define NFREQ  51
#define NELEM  (BATCH*NFREQ)      // 13056
#define NSAMP  80000
#define NBLK   (2*NSEG)           // 1600 K1 blocks (1 segment each)
#define NJ     16                 // reduce split
#define GPJ    (NSEG/NJ)          // 50 blocks per slab
#define XSTR   104                // shorts per staged row: k 0..99 + zeroed 100..103 (208 B, 16B-mult)

typedef __attribute__((ext_vector_type(8))) short          short8;    // 8 bf16 = 4 VGPR
typedef __attribute__((ext_vector_type(4))) float          float4v;   // MFMA acc
typedef __attribute__((ext_vector_type(4))) unsigned short ushort4v;

// ---------------- compile-time window + trig (double Taylor, exact to fp32) ----------------
constexpr double TCPI  = 3.14159265358979323846264338327950288;
constexpr double TC2PI = 6.28318530717958647692528676655900577;

constexpr double taylor_cos(double y) {   // |y| <= pi
    double y2 = y * y, term = 1.0, sum = 1.0;
    for (int j = 1; j <= 26; ++j) { term *= -y2 / (double)((2*j-1)*(2*j)); sum += term; }
    return sum;
}
constexpr double cos_k(int k) {           // cos(2*pi*(k%100)/100)
    return -taylor_cos(TC2PI * (double)(k % 100) / 100.0 - TCPI);
}
struct WinT { float w[100]; };
constexpr WinT make_win() {
    WinT t{};
    for (int k = 0; k < 100; ++k) t.w[k] = (float)(1.0 - cos_k(k));   // hann(periodic)*2
    return t;
}
__device__ const WinT d_wt = make_win();

struct TrigT { float c[100]; float s[100]; };
constexpr TrigT make_trig() {
    TrigT t{};
    for (int m = 0; m < 100; ++m) {
        t.c[m] = (float)cos_k(m);                 // cos(2*pi*m/100)
        t.s[m] = (float)cos_k((m + 75) % 100);    // sin = cos shifted by 3/4 period
    }
    return t;
}
__device__ const TrigT d_tt = make_trig();

// ---------------- bf16 helpers (RN-even) ----------------
__device__ __forceinline__ unsigned short f2bf(float x) {
    unsigned int u = __float_as_uint(x);
    return (unsigned short)((u + 0x7FFFu + ((u >> 16) & 1u)) >> 16);
}
__device__ __forceinline__ float bf2f(unsigned short h) {
    return __uint_as_float(((unsigned int)h) << 16);
}

// order-preserving float<->uint key (monotone; min/max commutative => deterministic)
__device__ __forceinline__ unsigned int f2key(float x) {
    unsigned int b = __float_as_uint(x);
    return (b & 0x80000000u) ? ~b : (b | 0x80000000u);
}
__device__ __forceinline__ float key2f(unsigned int k) {
    return __uint_as_float((k & 0x80000000u) ? (k ^ 0x80000000u) : ~k);
}

// ---------------- K0: twiddle tables in MFMA B-frag order ----------------
// tw[pt][lane][j], pt=(kt*4+nt)*4+typ, typ: 0=Chi 1=Clo 2=Shi 3=Slo
// B[k=quad*8+j][f=lane&15]; zero for f>=51 or k>=100  (the k>=100 zeros make
// the A-side garbage at k>=104 harmless: finite * 0 = 0)
__global__ void gen_tw_kernel(unsigned short* __restrict__ tw)
{
    int tid  = blockIdx.x * 256 + threadIdx.x;   // < 4096
    int lane = tid & 63, pt = tid >> 6;          // pt < 64
    int typ = pt & 3, nt = (pt >> 2) & 3, kt = pt >> 4;
    int f    = nt * 16 + (lane & 15);
    #pragma unroll
    for (int j = 0; j < 8; ++j) {
        int n = kt * 32 + (lane >> 4) * 8 + j;
        unsigned short outv = 0;
        if (f < 51 && n < 100) {
            int m = (n * f) % 100;
            float c = (typ < 2) ? d_tt.c[m] : d_tt.s[m];
            unsigned short h = f2bf(c);
            outv = (typ & 1) ? f2bf(c - bf2f(h)) : h;
        }
        tw[(pt << 9) + (lane << 3) + j] = outv;
    }
}

// ======== K1 macros — textual expansion, ALL private indices compile-time ========

// one frequency-half DFT: 64 MFMAs + PSD + signed-clamp-log into LV[2][2][4]
#define DFT_PASS(FH, LV)                                                           \
  {                                                                                \
    float4v aRe[2][2] = {}; float4v aIm[2][2] = {};                                \
    _Pragma("unroll")                                                              \
    for (int kt = 0; kt < 4; ++kt) {                                               \
      short8 xa0 = *(const short8*)(xsh + (32*wv +      col) * XSTR + kt*32 + quad*8); \
      short8 xa1 = *(const short8*)(xsh + (32*wv + 16 + col) * XSTR + kt*32 + quad*8); \
      _Pragma("unroll")                                                            \
      for (int ntl = 0; ntl < 2; ++ntl) {                                          \
        const unsigned short* bp_ = tw + ((kt*4 + (FH)*2 + ntl)*4)*512 + (lane<<3); \
        short8 bCh = *(const short8*)(bp_);                                        \
        short8 bCl = *(const short8*)(bp_ + 512);                                  \
        short8 bSh = *(const short8*)(bp_ + 1024);                                 \
        short8 bSl = *(const short8*)(bp_ + 1536);                                 \
        aRe[0][ntl] = __builtin_amdgcn_mfma_f32_16x16x32_bf16(xa0, bCh, aRe[0][ntl],0,0,0); \
        aRe[0][ntl] = __builtin_amdgcn_mfma_f32_16x16x32_bf16(xa0, bCl, aRe[0][ntl],0,0,0); \
        aIm[0][ntl] = __builtin_amdgcn_mfma_f32_16x16x32_bf16(xa0, bSh, aIm[0][ntl],0,0,0); \
        aIm[0][ntl] = __builtin_amdgcn_mfma_f32_16x16x32_bf16(xa0, bSl, aIm[0][ntl],0,0,0); \
        aRe[1][ntl] = __builtin_amdgcn_mfma_f32_16x16x32_bf16(xa1, bCh, aRe[1][ntl],0,0,0); \
        aRe[1][ntl] = __builtin_amdgcn_mfma_f32_16x16x32_bf16(xa1, bCl, aRe[1][ntl],0,0,0); \
        aIm[1][ntl] = __builtin_amdgcn_mfma_f32_16x16x32_bf16(xa1, bSh, aIm[1][ntl],0,0,0); \
        aIm[1][ntl] = __builtin_amdgcn_mfma_f32_16x16x32_bf16(xa1, bSl, aIm[1][ntl],0,0,0); \
      }                                                                            \
    }                                                                              \
    _Pragma("unroll")                                                              \
    for (int mt = 0; mt < 2; ++mt)                                                 \
      _Pragma("unroll")                                                            \
      for (int ntl = 0; ntl < 2; ++ntl)                                            \
        _Pragma("unroll")                                                          \
        for (int reg = 0; reg < 4; ++reg) {                                        \
          float re_ = aRe[mt][ntl][reg], im_ = aIm[mt][ntl][reg];                  \
          float p_  = fmaf(re_, re_, im_ * im_);                                   \
          p_        = fmaxf(p_, 1e-38f);                                           \
          float lv_ = __logf(p_);                                                  \
          float al_ = fmaxf(fabsf(lv_), 1e-6f);                                    \
          LV[mt][ntl][reg] = (lv_ > 0.0f) ? al_ : ((lv_ < 0.0f) ? -al_ : 0.0f);    \
        }                                                                          \
  }

#define MINMAX_ATOM(LV, FH)                                                        \
  _Pragma("unroll")                                                                \
  for (int mt = 0; mt < 2; ++mt)                                                   \
    _Pragma("unroll")                                                              \
    for (int ntl = 0; ntl < 2; ++ntl) {                                            \
      const int nt_ = (FH)*2 + ntl;                                                \
      if (nt_ < 3 || v3) {                                                         \
        _Pragma("unroll")                                                          \
        for (int reg = 0; reg < 4; ++reg) {                                        \
          int flat_ = (32*wv + 16*mt + quad*4 + reg) * 51 + nt_*16 + col;          \
          unsigned int key_ = f2key(LV[mt][ntl][reg]);                             \
          atomicMin(&mnU[flat_ & 255], key_);                                      \
          atomicMax(&mxU[flat_ & 255], key_);                                      \
        }                                                                          \
      }                                                                            \
    }

#define NORM_STORE(LV, FH)                                                         \
  _Pragma("unroll")                                                                \
  for (int mt = 0; mt < 2; ++mt)                                                   \
    _Pragma("unroll")                                                              \
    for (int ntl = 0; ntl < 2; ++ntl) {                                            \
      const int nt_ = (FH)*2 + ntl;                                                \
      if (nt_ < 3 || v3) {                                                         \
        _Pragma("unroll")                                                          \
        for (int reg = 0; reg < 4; ++reg) {                                        \
          int flat_ = (32*wv + 16*mt + quad*4 + reg) * 51 + nt_*16 + col;          \
          int c_    = flat_ & 255;                                                 \
          float mn_  = __uint_as_float(mnU[c_]);                                   \
          float inv_ = __uint_as_float(mxU[c_]);                                   \
          float F_ = (LV[mt][ntl][reg] - mn_) * inv_;                              \
          ssq = fmaf(F_, F_, ssq);                                                 \
          dst[flat_] = F_;                                                         \
        }                                                                          \
      }                                                                            \
    }

// ---------------- K1: per-segment MFMA DFT, 53.3 KB LDS -> 3 blocks/CU ----------------
// R1 register profile (acc 32 + Lv 32, nothing else persistent -> no spill).
// min/max via LDS atomic keys overlaid on dead xsh (no extra LDS, fewer phases).
__global__ void __launch_bounds__(512) __attribute__((amdgpu_waves_per_eu(6)))
psd_seg_kernel(const float* __restrict__ fake, const float* __restrict__ real,
               float* __restrict__ part, float* __restrict__ saArr,
               const unsigned short* __restrict__ tw)
{
    __shared__ __align__(16) unsigned char smem[53312];
    unsigned short* xsh  = (unsigned short*)smem;          // [256][104] staged bf16 x
    unsigned int*   mnU  = (unsigned int*)smem;            // overlay, valid after B2
    unsigned int*   mxU  = ((unsigned int*)smem) + 256;
    float*          red8 = (float*)(smem + 2048);          // overlay, valid after B5

    const int bx = blockIdx.x;              // < 1600
    const int a  = bx >= NSEG;
    const int s  = a ? bx - NSEG : bx;
    const int t  = threadIdx.x;
    const int lane = t & 63, wv = t >> 6;
    const int col = lane & 15, quad = lane >> 4;
    const bool v3 = (col < 3);              // f<51 for nt==3
    const float4* __restrict__ src4 = (const float4*)(a ? real : fake);
    const float4* __restrict__ w4   = (const float4*)d_wt.w;

    // ---- stage: 6400 coalesced float4 loads -> clamp/window -> bf16 short4 stores ----
    #pragma unroll
    for (int it = 0; it < 13; ++it) {
        int idx = t + it * 512;
        if (idx < 6400) {
            int row = idx / 25, q = idx - row * 25;          // q-th float4 of row
            float4 v  = src4[(size_t)row * (NSAMP / 4) + s * 25 + q];
            float4 ww = w4[q];
            ushort4v o;
            o.x = f2bf(fmaxf(v.x, 1e-6f) * ww.x);
            o.y = f2bf(fmaxf(v.y, 1e-6f) * ww.y);
            o.z = f2bf(fmaxf(v.z, 1e-6f) * ww.z);
            o.w = f2bf(fmaxf(v.w, 1e-6f) * ww.w);
            *(ushort4v*)(xsh + row * XSTR + 4 * q) = o;      // 8B-aligned
        }
    }
    // ---- zero-pad: k 100..103 per row (NaN guard; B=0 there anyway) ----
    if (t < 256) {
        ushort4v z = {0, 0, 0, 0};
        *(ushort4v*)(xsh + t * XSTR + 100) = z;
    }
    // ---- zero 64 B tail pad (row 255's kt=3 reads run past 256*104) ----
    if (t >= 256 && t < 264) {
        ushort4v z = {0, 0, 0, 0};
        *(ushort4v*)(xsh + 256 * XSTR + 4 * (t - 256)) = z;
    }
    __syncthreads();                                   // B1: xsh staged

    // ---- DFT both frequency halves; log-PSD in registers ----
    float LvA[2][2][4], LvB[2][2][4];
    DFT_PASS(0, LvA)
    DFT_PASS(1, LvB)
    __syncthreads();                                   // B2: all xsh reads retired

    // ---- init min/max overlay on dead xsh ----
    if (t < 256) mnU[t] = 0xFFFFFFFFu;
    else if (t < 512) mxU[t - 256] = 0u;
    __syncthreads();                                   // B3: overlay init visible

    MINMAX_ATOM(LvA, 0)
    MINMAX_ATOM(LvB, 1)
    __syncthreads();                                   // B4: atomics done

    if (t < 256) {
        float fmn = key2f(mnU[t]);
        float fmx = key2f(mxU[t]);
        mnU[t] = __float_as_uint(fmn);
        mxU[t] = __float_as_uint(1.0f / (fmx - fmn));
    }
    __syncthreads();                                   // B5: mn/inv finalized

    // ---- normalize from registers + coalesced-ish store + ssq ----
    float ssq = 0.0f;
    float* __restrict__ dst = part + (size_t)bx * NELEM;
    NORM_STORE(LvA, 0)
    NORM_STORE(LvB, 1)

    #pragma unroll
    for (int off = 32; off; off >>= 1) ssq += __shfl_down(ssq, off, 64);
    if (lane == 0) red8[wv] = ssq;
    __syncthreads();                                   // B6: red8 ready
    if (t == 0) {
        float acc = 0.0f;
        #pragma unroll
        for (int i = 0; i < 8; ++i) acc += red8[i];
        saArr[bx] = acc;
    }
}

// ---------------- K2a: partial column sums over 50-block slabs ----------------
__global__ void reduce_part_kernel(const float* __restrict__ part, float* __restrict__ pb)
{
    const int e = blockIdx.x * 256 + threadIdx.x;   // < 13056
    const int j = blockIdx.y;                        // < NJ
    const float* __restrict__ pF = part + (size_t)(j * GPJ) * NELEM + e;
    const float* __restrict__ pR = part + (size_t)(NSEG + j * GPJ) * NELEM + e;
    float sF = 0.0f, sR = 0.0f;
    #pragma unroll 5
    for (int i = 0; i < GPJ; ++i) {
        sF += pF[(size_t)i * NELEM];
        sR += pR[(size_t)i * NELEM];
    }
    pb[(size_t)(2 * j + 0) * NELEM + e] = sF;
    pb[(size_t)(2 * j + 1) * NELEM + e] = sR;
}

// ---------------- K2b: finish sums, per-e dot/ff, block reduce ----------------
__global__ void dot_kernel(const float* __restrict__ pb, double* __restrict__ k2out)
{
    __shared__ double red[2][4];
    const int t = threadIdx.x;
    const int e = blockIdx.x * 256 + t;
    float sF = 0.0f, sR = 0.0f;
    #pragma unroll
    for (int j = 0; j < NJ; ++j) {
        sF += pb[(size_t)(2 * j + 0) * NELEM + e];
        sR += pb[(size_t)(2 * j + 1) * NELEM + e];
    }
    double d  = (double)sF * (double)sR;
    double f2 = (double)sF * (double)sF;
    #pragma unroll
    for (int off = 32; off; off >>= 1) {
        d  += __shfl_down(d,  off, 64);
        f2 += __shfl_down(f2, off, 64);
    }
    if ((t & 63) == 0) { red[0][t >> 6] = d; red[1][t >> 6] = f2; }
    __syncthreads();
    if (t == 0) {
        k2out[2 * blockIdx.x + 0] = red[0][0] + red[0][1] + red[0][2] + red[0][3];
        k2out[2 * blockIdx.x + 1] = red[1][0] + red[1][1] + red[1][2] + red[1][3];
    }
}

// ---------------- K3: final combine in double ----------------
__global__ void final_kernel(const double* __restrict__ k2out, const float* __restrict__ saArr,
                             float* __restrict__ out)
{
    __shared__ double red[4][4];
    const int t = threadIdx.x;
    double d = 0.0, f2 = 0.0, sf = 0.0, sr = 0.0;
    if (t < NFREQ) { d = k2out[2 * t]; f2 = k2out[2 * t + 1]; }
    for (int i = t; i < NSEG; i += 256) {
        sf += (double)saArr[i];
        sr += (double)saArr[NSEG + i];
    }
    #pragma unroll
    for (int off = 32; off; off >>= 1) {
        d  += __shfl_down(d,  off, 64);
        f2 += __shfl_down(f2, off, 64);
        sf += __shfl_down(sf, off, 64);
        sr += __shfl_down(sr, off, 64);
    }
    const int w = t >> 6;
    if ((t & 63) == 0) { red[0][w] = d; red[1][w] = f2; red[2][w] = sf; red[3][w] = sr; }
    __syncthreads();
    if (t == 0) {
        double D  = red[0][0] + red[0][1] + red[0][2] + red[0][3];
        double FF = red[1][0] + red[1][1] + red[1][2] + red[1][3];
        double SF = red[2][0] + red[2][1] + red[2][2] + red[2][3];
        double SR = red[3][0] + red[3][1] + red[3][2] + red[3][3];

        const double n    = (double)NELEM;
        const double nseg = (double)NSEG;
        const double m    = nseg * (nseg - 1.0) * 0.5;

        out[0] = (float)((SF / nseg + SR / nseg - 2.0 * D / (nseg * nseg)) / n);
        out[1] = (float)((nseg * SF - FF) / (n * m));
    }
}

extern "C" void kernel_launch(void* const* d_in, const int* in_sizes, int n_in,
                              void* d_out, int out_size, void* d_ws, size_t ws_size,
                              hipStream_t stream) {
    const float* fake = (const float*)d_in[0];
    const float* real = (const float*)d_in[1];
    float* ws  = (float*)d_ws;
    float* out = (float*)d_out;

    // ws (floats): part[1600*13056] | saArr[1600] | pb[2*NJ*13056] | k2out (doubles) | tw (64KB)
    const size_t SA_FL = (size_t)NBLK * NELEM;            // 20,889,600
    const size_t PB_FL = SA_FL + NBLK;
    const size_t K2_BY = (PB_FL + (size_t)2 * NJ * NELEM) * 4;         // 8B-aligned
    const size_t TW_BY = (K2_BY + 2 * NFREQ * sizeof(double) + 63) & ~(size_t)63;

    float*          sa = ws + SA_FL;
    float*          pb = ws + PB_FL;
    double*         k2 = (double*)((char*)d_ws + K2_BY);
    unsigned short* tw = (unsigned short*)((char*)d_ws + TW_BY);

    gen_tw_kernel<<<16, 256, 0, stream>>>(tw);
    psd_seg_kernel<<<NBLK, 512, 0, stream>>>(fake, real, ws, sa, tw);
    reduce_part_kernel<<<dim3(NFREQ, NJ), 256, 0, stream>>>(ws, pb);
    dot_kernel<<<NFREQ, 256, 0, stream>>>(pb, k2);
    final_kernel<<<1, 256, 0, stream>>>(k2, sa, out);
}

// Round 6
// 260.637 us; speedup vs baseline: 2.2352x; 1.2539x over previous
//
#include <hip/hip_runtime.h>

#define NSEG   800
#define BATCH  256
#define NFREQ  51
#define NELEM  (BATCH*NFREQ)      // 13056
#define NSAMP  80000
#define NBLK   (2*NSEG)           // 1600 K1 blocks (1 segment each)
#define NJ     16                 // reduce split
#define GPJ    (NSEG/NJ)          // 50 blocks per slab
#define XSTR   104                // shorts per staged row: k 0..99 + zeroed 100..103 (208 B, 16B-mult)

typedef __attribute__((ext_vector_type(8))) short          short8;    // 8 bf16 = 4 VGPR
typedef __attribute__((ext_vector_type(4))) float          float4v;   // MFMA acc
typedef __attribute__((ext_vector_type(4))) unsigned short ushort4v;

// ---------------- compile-time window + trig (double Taylor, exact to fp32) ----------------
constexpr double TCPI  = 3.14159265358979323846264338327950288;
constexpr double TC2PI = 6.28318530717958647692528676655900577;

constexpr double taylor_cos(double y) {   // |y| <= pi
    double y2 = y * y, term = 1.0, sum = 1.0;
    for (int j = 1; j <= 26; ++j) { term *= -y2 / (double)((2*j-1)*(2*j)); sum += term; }
    return sum;
}
constexpr double cos_k(int k) {           // cos(2*pi*(k%100)/100)
    return -taylor_cos(TC2PI * (double)(k % 100) / 100.0 - TCPI);
}
struct WinT { float w[100]; };
constexpr WinT make_win() {
    WinT t{};
    for (int k = 0; k < 100; ++k) t.w[k] = (float)(1.0 - cos_k(k));   // hann(periodic)*2
    return t;
}
__device__ const WinT d_wt = make_win();

struct TrigT { float c[100]; float s[100]; };
constexpr TrigT make_trig() {
    TrigT t{};
    for (int m = 0; m < 100; ++m) {
        t.c[m] = (float)cos_k(m);                 // cos(2*pi*m/100)
        t.s[m] = (float)cos_k((m + 75) % 100);    // sin = cos shifted by 3/4 period
    }
    return t;
}
__device__ const TrigT d_tt = make_trig();

// ---------------- bf16 helpers (RN-even) ----------------
__device__ __forceinline__ unsigned short f2bf(float x) {
    unsigned int u = __float_as_uint(x);
    return (unsigned short)((u + 0x7FFFu + ((u >> 16) & 1u)) >> 16);
}
__device__ __forceinline__ float bf2f(unsigned short h) {
    return __uint_as_float(((unsigned int)h) << 16);
}

// order-preserving float<->uint key (monotone; min/max commutative => deterministic)
__device__ __forceinline__ unsigned int f2key(float x) {
    unsigned int b = __float_as_uint(x);
    return (b & 0x80000000u) ? ~b : (b | 0x80000000u);
}
__device__ __forceinline__ float key2f(unsigned int k) {
    return __uint_as_float((k & 0x80000000u) ? (k ^ 0x80000000u) : ~k);
}

// ---------------- K0: twiddle tables in MFMA B-frag order ----------------
// tw[pt][lane][j], pt=(kt*4+nt)*4+typ, typ: 0=Chi 1=Clo 2=Shi 3=Slo
// B[k=quad*8+j][f=lane&15]; zero for f>=51 or k>=100  (the k>=100 zeros make
// the A-side garbage at k>=104 harmless: finite * 0 = 0)
__global__ void gen_tw_kernel(unsigned short* __restrict__ tw)
{
    int tid  = blockIdx.x * 256 + threadIdx.x;   // < 4096
    int lane = tid & 63, pt = tid >> 6;          // pt < 64
    int typ = pt & 3, nt = (pt >> 2) & 3, kt = pt >> 4;
    int f    = nt * 16 + (lane & 15);
    #pragma unroll
    for (int j = 0; j < 8; ++j) {
        int n = kt * 32 + (lane >> 4) * 8 + j;
        unsigned short outv = 0;
        if (f < 51 && n < 100) {
            int m = (n * f) % 100;
            float c = (typ < 2) ? d_tt.c[m] : d_tt.s[m];
            unsigned short h = f2bf(c);
            outv = (typ & 1) ? f2bf(c - bf2f(h)) : h;
        }
        tw[(pt << 9) + (lane << 3) + j] = outv;
    }
}

// ======== K1 macros — textual expansion, ALL private indices compile-time ========

// one frequency-half DFT: 64 MFMAs + PSD + signed-clamp-log into LV[2][2][4]
#define DFT_PASS(FH, LV)                                                           \
  {                                                                                \
    float4v aRe[2][2] = {}; float4v aIm[2][2] = {};                                \
    _Pragma("unroll")                                                              \
    for (int kt = 0; kt < 4; ++kt) {                                               \
      short8 xa0 = *(const short8*)(xsh + (32*wv +      col) * XSTR + kt*32 + quad*8); \
      short8 xa1 = *(const short8*)(xsh + (32*wv + 16 + col) * XSTR + kt*32 + quad*8); \
      _Pragma("unroll")                                                            \
      for (int ntl = 0; ntl < 2; ++ntl) {                                          \
        const unsigned short* bp_ = tw + ((kt*4 + (FH)*2 + ntl)*4)*512 + (lane<<3); \
        short8 bCh = *(const short8*)(bp_);                                        \
        short8 bCl = *(const short8*)(bp_ + 512);                                  \
        short8 bSh = *(const short8*)(bp_ + 1024);                                 \
        short8 bSl = *(const short8*)(bp_ + 1536);                                 \
        aRe[0][ntl] = __builtin_amdgcn_mfma_f32_16x16x32_bf16(xa0, bCh, aRe[0][ntl],0,0,0); \
        aRe[0][ntl] = __builtin_amdgcn_mfma_f32_16x16x32_bf16(xa0, bCl, aRe[0][ntl],0,0,0); \
        aIm[0][ntl] = __builtin_amdgcn_mfma_f32_16x16x32_bf16(xa0, bSh, aIm[0][ntl],0,0,0); \
        aIm[0][ntl] = __builtin_amdgcn_mfma_f32_16x16x32_bf16(xa0, bSl, aIm[0][ntl],0,0,0); \
        aRe[1][ntl] = __builtin_amdgcn_mfma_f32_16x16x32_bf16(xa1, bCh, aRe[1][ntl],0,0,0); \
        aRe[1][ntl] = __builtin_amdgcn_mfma_f32_16x16x32_bf16(xa1, bCl, aRe[1][ntl],0,0,0); \
        aIm[1][ntl] = __builtin_amdgcn_mfma_f32_16x16x32_bf16(xa1, bSh, aIm[1][ntl],0,0,0); \
        aIm[1][ntl] = __builtin_amdgcn_mfma_f32_16x16x32_bf16(xa1, bSl, aIm[1][ntl],0,0,0); \
      }                                                                            \
    }                                                                              \
    _Pragma("unroll")                                                              \
    for (int mt = 0; mt < 2; ++mt)                                                 \
      _Pragma("unroll")                                                            \
      for (int ntl = 0; ntl < 2; ++ntl)                                            \
        _Pragma("unroll")                                                          \
        for (int reg = 0; reg < 4; ++reg) {                                        \
          float re_ = aRe[mt][ntl][reg], im_ = aIm[mt][ntl][reg];                  \
          float p_  = fmaf(re_, re_, im_ * im_);                                   \
          p_        = fmaxf(p_, 1e-38f);                                           \
          float lv_ = __logf(p_);                                                  \
          float al_ = fmaxf(fabsf(lv_), 1e-6f);                                    \
          LV[mt][ntl][reg] = (lv_ > 0.0f) ? al_ : ((lv_ < 0.0f) ? -al_ : 0.0f);    \
        }                                                                          \
  }

#define MINMAX_ATOM(LV, FH)                                                        \
  _Pragma("unroll")                                                                \
  for (int mt = 0; mt < 2; ++mt)                                                   \
    _Pragma("unroll")                                                              \
    for (int ntl = 0; ntl < 2; ++ntl) {                                            \
      const int nt_ = (FH)*2 + ntl;                                                \
      if (nt_ < 3 || v3) {                                                         \
        _Pragma("unroll")                                                          \
        for (int reg = 0; reg < 4; ++reg) {                                        \
          int flat_ = (32*wv + 16*mt + quad*4 + reg) * 51 + nt_*16 + col;          \
          unsigned int key_ = f2key(LV[mt][ntl][reg]);                             \
          atomicMin(&mnU[flat_ & 255], key_);                                      \
          atomicMax(&mxU[flat_ & 255], key_);                                      \
        }                                                                          \
      }                                                                            \
    }

#define NORM_STORE(LV, FH)                                                         \
  _Pragma("unroll")                                                                \
  for (int mt = 0; mt < 2; ++mt)                                                   \
    _Pragma("unroll")                                                              \
    for (int ntl = 0; ntl < 2; ++ntl) {                                            \
      const int nt_ = (FH)*2 + ntl;                                                \
      if (nt_ < 3 || v3) {                                                         \
        _Pragma("unroll")                                                          \
        for (int reg = 0; reg < 4; ++reg) {                                        \
          int flat_ = (32*wv + 16*mt + quad*4 + reg) * 51 + nt_*16 + col;          \
          int c_    = flat_ & 255;                                                 \
          float mn_  = __uint_as_float(mnU[c_]);                                   \
          float inv_ = __uint_as_float(mxU[c_]);                                   \
          float F_ = (LV[mt][ntl][reg] - mn_) * inv_;                              \
          ssq = fmaf(F_, F_, ssq);                                                 \
          dst[flat_] = F_;                                                         \
        }                                                                          \
      }                                                                            \
    }

// ---------------- K1: per-segment MFMA DFT, 53.3 KB LDS -> 3 blocks/CU ----------------
// waves_per_eu(4): compiler budget = 256/4 = 64 VGPR (R1-proven spill-free for this
// code shape). Runtime occupancy comes from resources: VGPR 64 -> 8 waves/EU possible,
// LDS 53760 B -> 3 blocks/CU = 6 waves/EU.  (waves_per_eu(6) gave a 40-VGPR budget
// and catastrophic spill — R5 post-mortem.)
__global__ void __launch_bounds__(512) __attribute__((amdgpu_waves_per_eu(4)))
psd_seg_kernel(const float* __restrict__ fake, const float* __restrict__ real,
               float* __restrict__ part, float* __restrict__ saArr,
               const unsigned short* __restrict__ tw)
{
    __shared__ __align__(16) unsigned char smem[53312];
    unsigned short* xsh  = (unsigned short*)smem;          // [256][104] staged bf16 x
    unsigned int*   mnU  = (unsigned int*)smem;            // overlay, valid after B2
    unsigned int*   mxU  = ((unsigned int*)smem) + 256;
    float*          red8 = (float*)(smem + 2048);          // overlay, valid after B5

    const int bx = blockIdx.x;              // < 1600
    const int a  = bx >= NSEG;
    const int s  = a ? bx - NSEG : bx;
    const int t  = threadIdx.x;
    const int lane = t & 63, wv = t >> 6;
    const int col = lane & 15, quad = lane >> 4;
    const bool v3 = (col < 3);              // f<51 for nt==3
    const float4* __restrict__ src4 = (const float4*)(a ? real : fake);
    const float4* __restrict__ w4   = (const float4*)d_wt.w;

    // ---- stage: 6400 coalesced float4 loads -> clamp/window -> bf16 short4 stores ----
    #pragma unroll
    for (int it = 0; it < 13; ++it) {
        int idx = t + it * 512;
        if (idx < 6400) {
            int row = idx / 25, q = idx - row * 25;          // q-th float4 of row
            float4 v  = src4[(size_t)row * (NSAMP / 4) + s * 25 + q];
            float4 ww = w4[q];
            ushort4v o;
            o.x = f2bf(fmaxf(v.x, 1e-6f) * ww.x);
            o.y = f2bf(fmaxf(v.y, 1e-6f) * ww.y);
            o.z = f2bf(fmaxf(v.z, 1e-6f) * ww.z);
            o.w = f2bf(fmaxf(v.w, 1e-6f) * ww.w);
            *(ushort4v*)(xsh + row * XSTR + 4 * q) = o;      // 8B-aligned
        }
    }
    // ---- zero-pad: k 100..103 per row (NaN guard; B=0 there anyway) ----
    if (t < 256) {
        ushort4v z = {0, 0, 0, 0};
        *(ushort4v*)(xsh + t * XSTR + 100) = z;
    }
    // ---- zero 64 B tail pad (row 255's kt=3 reads run past 256*104) ----
    if (t >= 256 && t < 264) {
        ushort4v z = {0, 0, 0, 0};
        *(ushort4v*)(xsh + 256 * XSTR + 4 * (t - 256)) = z;
    }
    __syncthreads();                                   // B1: xsh staged

    // ---- DFT both frequency halves; log-PSD in registers ----
    float LvA[2][2][4], LvB[2][2][4];
    DFT_PASS(0, LvA)
    DFT_PASS(1, LvB)
    __syncthreads();                                   // B2: all xsh reads retired

    // ---- init min/max overlay on dead xsh ----
    if (t < 256) mnU[t] = 0xFFFFFFFFu;
    else if (t < 512) mxU[t - 256] = 0u;
    __syncthreads();                                   // B3: overlay init visible

    MINMAX_ATOM(LvA, 0)
    MINMAX_ATOM(LvB, 1)
    __syncthreads();                                   // B4: atomics done

    if (t < 256) {
        float fmn = key2f(mnU[t]);
        float fmx = key2f(mxU[t]);
        mnU[t] = __float_as_uint(fmn);
        mxU[t] = __float_as_uint(1.0f / (fmx - fmn));
    }
    __syncthreads();                                   // B5: mn/inv finalized

    // ---- normalize from registers + store + ssq ----
    float ssq = 0.0f;
    float* __restrict__ dst = part + (size_t)bx * NELEM;
    NORM_STORE(LvA, 0)
    NORM_STORE(LvB, 1)

    #pragma unroll
    for (int off = 32; off; off >>= 1) ssq += __shfl_down(ssq, off, 64);
    if (lane == 0) red8[wv] = ssq;
    __syncthreads();                                   // B6: red8 ready
    if (t == 0) {
        float acc = 0.0f;
        #pragma unroll
        for (int i = 0; i < 8; ++i) acc += red8[i];
        saArr[bx] = acc;
    }
}

// ---------------- K2a: partial column sums over 50-block slabs ----------------
__global__ void reduce_part_kernel(const float* __restrict__ part, float* __restrict__ pb)
{
    const int e = blockIdx.x * 256 + threadIdx.x;   // < 13056
    const int j = blockIdx.y;                        // < NJ
    const float* __restrict__ pF = part + (size_t)(j * GPJ) * NELEM + e;
    const float* __restrict__ pR = part + (size_t)(NSEG + j * GPJ) * NELEM + e;
    float sF = 0.0f, sR = 0.0f;
    #pragma unroll 5
    for (int i = 0; i < GPJ; ++i) {
        sF += pF[(size_t)i * NELEM];
        sR += pR[(size_t)i * NELEM];
    }
    pb[(size_t)(2 * j + 0) * NELEM + e] = sF;
    pb[(size_t)(2 * j + 1) * NELEM + e] = sR;
}

// ---------------- K2b: finish sums, per-e dot/ff, block reduce ----------------
__global__ void dot_kernel(const float* __restrict__ pb, double* __restrict__ k2out)
{
    __shared__ double red[2][4];
    const int t = threadIdx.x;
    const int e = blockIdx.x * 256 + t;
    float sF = 0.0f, sR = 0.0f;
    #pragma unroll
    for (int j = 0; j < NJ; ++j) {
        sF += pb[(size_t)(2 * j + 0) * NELEM + e];
        sR += pb[(size_t)(2 * j + 1) * NELEM + e];
    }
    double d  = (double)sF * (double)sR;
    double f2 = (double)sF * (double)sF;
    #pragma unroll
    for (int off = 32; off; off >>= 1) {
        d  += __shfl_down(d,  off, 64);
        f2 += __shfl_down(f2, off, 64);
    }
    if ((t & 63) == 0) { red[0][t >> 6] = d; red[1][t >> 6] = f2; }
    __syncthreads();
    if (t == 0) {
        k2out[2 * blockIdx.x + 0] = red[0][0] + red[0][1] + red[0][2] + red[0][3];
        k2out[2 * blockIdx.x + 1] = red[1][0] + red[1][1] + red[1][2] + red[1][3];
    }
}

// ---------------- K3: final combine in double ----------------
__global__ void final_kernel(const double* __restrict__ k2out, const float* __restrict__ saArr,
                             float* __restrict__ out)
{
    __shared__ double red[4][4];
    const int t = threadIdx.x;
    double d = 0.0, f2 = 0.0, sf = 0.0, sr = 0.0;
    if (t < NFREQ) { d = k2out[2 * t]; f2 = k2out[2 * t + 1]; }
    for (int i = t; i < NSEG; i += 256) {
        sf += (double)saArr[i];
        sr += (double)saArr[NSEG + i];
    }
    #pragma unroll
    for (int off = 32; off; off >>= 1) {
        d  += __shfl_down(d,  off, 64);
        f2 += __shfl_down(f2, off, 64);
        sf += __shfl_down(sf, off, 64);
        sr += __shfl_down(sr, off, 64);
    }
    const int w = t >> 6;
    if ((t & 63) == 0) { red[0][w] = d; red[1][w] = f2; red[2][w] = sf; red[3][w] = sr; }
    __syncthreads();
    if (t == 0) {
        double D  = red[0][0] + red[0][1] + red[0][2] + red[0][3];
        double FF = red[1][0] + red[1][1] + red[1][2] + red[1][3];
        double SF = red[2][0] + red[2][1] + red[2][2] + red[2][3];
        double SR = red[3][0] + red[3][1] + red[3][2] + red[3][3];

        const double n    = (double)NELEM;
        const double nseg = (double)NSEG;
        const double m    = nseg * (nseg - 1.0) * 0.5;

        out[0] = (float)((SF / nseg + SR / nseg - 2.0 * D / (nseg * nseg)) / n);
        out[1] = (float)((nseg * SF - FF) / (n * m));
    }
}

extern "C" void kernel_launch(void* const* d_in, const int* in_sizes, int n_in,
                              void* d_out, int out_size, void* d_ws, size_t ws_size,
                              hipStream_t stream) {
    const float* fake = (const float*)d_in[0];
    const float* real = (const float*)d_in[1];
    float* ws  = (float*)d_ws;
    float* out = (float*)d_out;

    // ws (floats): part[1600*13056] | saArr[1600] | pb[2*NJ*13056] | k2out (doubles) | tw (64KB)
    const size_t SA_FL = (size_t)NBLK * NELEM;            // 20,889,600
    const size_t PB_FL = SA_FL + NBLK;
    const size_t K2_BY = (PB_FL + (size_t)2 * NJ * NELEM) * 4;         // 8B-aligned
    const size_t TW_BY = (K2_BY + 2 * NFREQ * sizeof(double) + 63) & ~(size_t)63;

    float*          sa = ws + SA_FL;
    float*          pb = ws + PB_FL;
    double*         k2 = (double*)((char*)d_ws + K2_BY);
    unsigned short* tw = (unsigned short*)((char*)d_ws + TW_BY);

    gen_tw_kernel<<<16, 256, 0, stream>>>(tw);
    psd_seg_kernel<<<NBLK, 512, 0, stream>>>(fake, real, ws, sa, tw);
    reduce_part_kernel<<<dim3(NFREQ, NJ), 256, 0, stream>>>(ws, pb);
    dot_kernel<<<NFREQ, 256, 0, stream>>>(pb, k2);
    final_kernel<<<1, 256, 0, stream>>>(k2, sa, out);
}